// Round 1
// baseline (2668.647 us; speedup 1.0000x reference)
//
#include <hip/hip_runtime.h>
#include <hip/hip_bf16.h>
#include <cstddef>

#define DIM   1024
#define NH    16
#define HD    64
#define BATCH 2
#define SEQ   2048
#define NROWS (BATCH * SEQ)   // 4096

// ---------------------------------------------------------------------------
// Kernel 1: qkv = x @ W_qkv + b_qkv, scattered to Q/K/V in [B,H,T,D] layout.
// M=4096, N=3072, K=1024. 64x64 tile, BK=16, 256 threads, 4x4 micro-tile.
// ---------------------------------------------------------------------------
__global__ __launch_bounds__(256) void qkv_gemm(
    const float* __restrict__ x, const float* __restrict__ W,
    const float* __restrict__ bias,
    float* __restrict__ Q, float* __restrict__ K, float* __restrict__ V) {
  const int bn = blockIdx.x;          // 0..47  (N/64)
  const int bm = blockIdx.y;          // 0..63  (M/64)
  const int tid = threadIdx.x;
  const int tx = tid & 15;            // n-direction
  const int ty = tid >> 4;            // m-direction
  const int row0 = bm * 64, col0 = bn * 64;

  __shared__ float As[16][68];        // [k][m], stride 68 -> 16B-aligned rows
  __shared__ float Bs[16][68];        // [k][n]

  float acc[4][4] = {};

  for (int k0 = 0; k0 < DIM; k0 += 16) {
    // A tile: thread t loads float4 of x[row0 + t/4][k0 + (t%4)*4 ..]
    {
      int m  = tid >> 2;
      int kk = (tid & 3) * 4;
      float4 v = *(const float4*)(x + (size_t)(row0 + m) * DIM + k0 + kk);
      As[kk + 0][m] = v.x; As[kk + 1][m] = v.y;
      As[kk + 2][m] = v.z; As[kk + 3][m] = v.w;
    }
    // B tile: thread t loads float4 of W[k0 + t/16][col0 + (t%16)*4 ..]
    {
      int kk = tid >> 4;
      int n  = (tid & 15) * 4;
      float4 v = *(const float4*)(W + (size_t)(k0 + kk) * 3072 + col0 + n);
      *(float4*)&Bs[kk][n] = v;
    }
    __syncthreads();
#pragma unroll
    for (int kk = 0; kk < 16; ++kk) {
      float4 av = *(const float4*)&As[kk][ty * 4];
      float4 bv = *(const float4*)&Bs[kk][tx * 4];
      float a[4] = {av.x, av.y, av.z, av.w};
      float b[4] = {bv.x, bv.y, bv.z, bv.w};
#pragma unroll
      for (int i = 0; i < 4; ++i)
#pragma unroll
        for (int j = 0; j < 4; ++j) acc[i][j] += a[i] * b[j];
    }
    __syncthreads();
  }

  // Epilogue: bias + scatter. All 64 cols of this tile share `which` and `h`.
#pragma unroll
  for (int i = 0; i < 4; ++i) {
    int r = row0 + ty * 4 + i;
    int b = r >> 11;          // / 2048
    int t = r & 2047;
#pragma unroll
    for (int j = 0; j < 4; ++j) {
      int c = col0 + tx * 4 + j;
      float val = acc[i][j] + bias[c];
      int which = c >> 10;
      int rem   = c & 1023;
      int h     = rem >> 6;
      int d     = rem & 63;
      float* dst = (which == 0) ? Q : ((which == 1) ? K : V);
      dst[(((size_t)(b * NH + h)) * SEQ + t) * HD + d] = val;
    }
  }
}

// ---------------------------------------------------------------------------
// Kernel 2: flash-style causal attention, fp32.
// One thread = one q row (q[64], o[64] in regs). Block = 1 wave = 64 q rows
// of one (b,h). K/V staged in LDS in 32-row tiles. Online softmax.
// Grid: 1024 blocks; chunk in low bits for causal load-balance interleave.
// ---------------------------------------------------------------------------
#define KT 32
__global__ __launch_bounds__(64, 2) void flash_attn(
    const float* __restrict__ Q, const float* __restrict__ Kg,
    const float* __restrict__ Vg, float* __restrict__ A) {
  const int blk   = blockIdx.x;       // 0..1023
  const int chunk = blk & 31;         // 32 chunks of 64 rows per (b,h)
  const int bh    = blk >> 5;         // 0..31
  const int q0    = chunk * 64;
  const int lane  = threadIdx.x;      // 0..63
  const int qi    = q0 + lane;

  __shared__ float Ks[KT][HD];
  __shared__ float Vs[KT][HD];

  float q[HD], o[HD];
  {
    const float4* qptr = (const float4*)(Q + ((size_t)bh * SEQ + qi) * HD);
#pragma unroll
    for (int i = 0; i < 16; ++i) {
      float4 v = qptr[i];
      q[i * 4 + 0] = v.x; q[i * 4 + 1] = v.y;
      q[i * 4 + 2] = v.z; q[i * 4 + 3] = v.w;
      o[i * 4 + 0] = 0.f; o[i * 4 + 1] = 0.f;
      o[i * 4 + 2] = 0.f; o[i * 4 + 3] = 0.f;
    }
  }

  float m = -3.0e38f, l = 0.f;
  const int kmax = q0 + 63;           // largest key this block needs
  const size_t kvbase = (size_t)bh * SEQ * HD;

  for (int k0 = 0; k0 <= kmax; k0 += KT) {
    // Stage K/V tile: 32 rows x 64 floats = 512 float4s, 8 per lane.
#pragma unroll
    for (int j = 0; j < 8; ++j) {
      int f  = lane + 64 * j;         // 0..511
      int kk = f >> 4;
      int dd = (f & 15) * 4;
      *(float4*)&Ks[kk][dd] =
          *(const float4*)(Kg + kvbase + (size_t)(k0 + kk) * HD + dd);
      *(float4*)&Vs[kk][dd] =
          *(const float4*)(Vg + kvbase + (size_t)(k0 + kk) * HD + dd);
    }
    __syncthreads();

    float s[KT];
    float mt = m;
#pragma unroll
    for (int kk = 0; kk < KT; ++kk) {
      float acc = 0.f;
#pragma unroll
      for (int d = 0; d < HD; d += 4) {
        float4 kv = *(const float4*)&Ks[kk][d];
        acc += q[d] * kv.x + q[d + 1] * kv.y + q[d + 2] * kv.z + q[d + 3] * kv.w;
      }
      acc *= 0.125f;                   // 1/sqrt(64)
      s[kk] = (k0 + kk <= qi) ? acc : -3.0e38f;
      mt = fmaxf(mt, s[kk]);
    }
    float alpha = __expf(m - mt);
    m = mt;
    l *= alpha;
#pragma unroll
    for (int d = 0; d < HD; ++d) o[d] *= alpha;
#pragma unroll
    for (int kk = 0; kk < KT; ++kk) {
      float p = __expf(s[kk] - m);
      l += p;
#pragma unroll
      for (int d = 0; d < HD; d += 4) {
        float4 vv = *(const float4*)&Vs[kk][d];
        o[d] += p * vv.x; o[d + 1] += p * vv.y;
        o[d + 2] += p * vv.z; o[d + 3] += p * vv.w;
      }
    }
    __syncthreads();
  }

  float inv = 1.0f / l;
  // A[b][t][h*64 + d]
  float4* optr = (float4*)(A + ((size_t)(bh >> 4) * SEQ + qi) * DIM +
                           (size_t)(bh & 15) * HD);
#pragma unroll
  for (int i = 0; i < 16; ++i) {
    float4 v = {o[i * 4 + 0] * inv, o[i * 4 + 1] * inv,
                o[i * 4 + 2] * inv, o[i * 4 + 3] * inv};
    optr[i] = v;
  }
}

// ---------------------------------------------------------------------------
// Kernel 3: out = A @ W_proj + b_proj. M=4096, N=1024, K=1024.
// ---------------------------------------------------------------------------
__global__ __launch_bounds__(256) void proj_gemm(
    const float* __restrict__ A, const float* __restrict__ W,
    const float* __restrict__ bias, float* __restrict__ out) {
  const int bn = blockIdx.x;          // 0..15
  const int bm = blockIdx.y;          // 0..63
  const int tid = threadIdx.x;
  const int tx = tid & 15;
  const int ty = tid >> 4;
  const int row0 = bm * 64, col0 = bn * 64;

  __shared__ float As[16][68];
  __shared__ float Bs[16][68];

  float acc[4][4] = {};

  for (int k0 = 0; k0 < DIM; k0 += 16) {
    {
      int m  = tid >> 2;
      int kk = (tid & 3) * 4;
      float4 v = *(const float4*)(A + (size_t)(row0 + m) * DIM + k0 + kk);
      As[kk + 0][m] = v.x; As[kk + 1][m] = v.y;
      As[kk + 2][m] = v.z; As[kk + 3][m] = v.w;
    }
    {
      int kk = tid >> 4;
      int n  = (tid & 15) * 4;
      float4 v = *(const float4*)(W + (size_t)(k0 + kk) * DIM + col0 + n);
      *(float4*)&Bs[kk][n] = v;
    }
    __syncthreads();
#pragma unroll
    for (int kk = 0; kk < 16; ++kk) {
      float4 av = *(const float4*)&As[kk][ty * 4];
      float4 bv = *(const float4*)&Bs[kk][tx * 4];
      float a[4] = {av.x, av.y, av.z, av.w};
      float b[4] = {bv.x, bv.y, bv.z, bv.w};
#pragma unroll
      for (int i = 0; i < 4; ++i)
#pragma unroll
        for (int j = 0; j < 4; ++j) acc[i][j] += a[i] * b[j];
    }
    __syncthreads();
  }

#pragma unroll
  for (int i = 0; i < 4; ++i) {
    int r = row0 + ty * 4 + i;
#pragma unroll
    for (int j = 0; j < 4; ++j) {
      int c = col0 + tx * 4 + j;
      out[(size_t)r * DIM + c] = acc[i][j] + bias[c];
    }
  }
}

// ---------------------------------------------------------------------------
extern "C" void kernel_launch(void* const* d_in, const int* in_sizes, int n_in,
                              void* d_out, int out_size, void* d_ws, size_t ws_size,
                              hipStream_t stream) {
  const float* x      = (const float*)d_in[0];
  const float* W_qkv  = (const float*)d_in[1];
  const float* b_qkv  = (const float*)d_in[2];
  const float* W_proj = (const float*)d_in[3];
  const float* b_proj = (const float*)d_in[4];
  float* out = (float*)d_out;

  const size_t qkv_elems = (size_t)BATCH * NH * SEQ * HD;  // 4M floats
  float* Q = (float*)d_ws;
  float* K = Q + qkv_elems;
  float* V = K + qkv_elems;
  float* A = V + qkv_elems;                                 // [B,T,C]

  dim3 g1(3072 / 64, NROWS / 64);
  qkv_gemm<<<g1, 256, 0, stream>>>(x, W_qkv, b_qkv, Q, K, V);

  flash_attn<<<dim3(BATCH * NH * (SEQ / 64)), 64, 0, stream>>>(Q, K, V, A);

  dim3 g3(DIM / 64, NROWS / 64);
  proj_gemm<<<g3, 256, 0, stream>>>(A, W_proj, b_proj, out);
}

// Round 2
// 693.572 us; speedup vs baseline: 3.8477x; 3.8477x over previous
//
#include <hip/hip_runtime.h>
#include <hip/hip_bf16.h>
#include <cstddef>
#include <cstdint>

#define DIM   1024
#define NH    16
#define HD    64
#define BATCH 2
#define SEQ   2048
#define NROWS (BATCH * SEQ)   // 4096
#define PADW  72              // LDS row stride in ushorts (144B = 9*16B)

typedef __bf16 bfrag  __attribute__((ext_vector_type(8)));
typedef float  f32x4  __attribute__((ext_vector_type(4)));

__device__ __forceinline__ unsigned short f2bf(float f) {
  union { float f; uint32_t u; } v; v.f = f;
  uint32_t r = (v.u + 0x7FFF + ((v.u >> 16) & 1)) >> 16;
  return (unsigned short)r;
}

// ---------------------------------------------------------------------------
// Kernel 1: qkv = x @ W_qkv + b_qkv  ->  bf16 Q[bh][t][d], K[bh][t][d],
// Vt[bh][d][t].  M=4096, N=3072, K=1024. 64x64 tile, 256 thr, 4x4 micro.
// ---------------------------------------------------------------------------
__global__ __launch_bounds__(256) void qkv_gemm(
    const float* __restrict__ x, const float* __restrict__ W,
    const float* __restrict__ bias,
    unsigned short* __restrict__ Qb, unsigned short* __restrict__ Kb,
    unsigned short* __restrict__ Vtb) {
  const int bn = blockIdx.x;          // 0..47
  const int bm = blockIdx.y;          // 0..63
  const int tid = threadIdx.x;
  const int tx = tid & 15;            // n
  const int ty = tid >> 4;            // m
  const int row0 = bm * 64, col0 = bn * 64;

  __shared__ float As[16][68];
  __shared__ float Bs[16][68];

  float acc[4][4] = {};

  for (int k0 = 0; k0 < DIM; k0 += 16) {
    {
      int m  = tid >> 2;
      int kk = (tid & 3) * 4;
      float4 v = *(const float4*)(x + (size_t)(row0 + m) * DIM + k0 + kk);
      As[kk + 0][m] = v.x; As[kk + 1][m] = v.y;
      As[kk + 2][m] = v.z; As[kk + 3][m] = v.w;
    }
    {
      int kk = tid >> 4;
      int n  = (tid & 15) * 4;
      float4 v = *(const float4*)(W + (size_t)(k0 + kk) * 3072 + col0 + n);
      *(float4*)&Bs[kk][n] = v;
    }
    __syncthreads();
#pragma unroll
    for (int kk = 0; kk < 16; ++kk) {
      float4 av = *(const float4*)&As[kk][ty * 4];
      float4 bv = *(const float4*)&Bs[kk][tx * 4];
      float a[4] = {av.x, av.y, av.z, av.w};
      float b[4] = {bv.x, bv.y, bv.z, bv.w};
#pragma unroll
      for (int i = 0; i < 4; ++i)
#pragma unroll
        for (int j = 0; j < 4; ++j) acc[i][j] += a[i] * b[j];
    }
    __syncthreads();
  }

  // Epilogue: bias + bf16 convert + scatter.
  const int c0    = col0 + tx * 4;
  const int which = c0 >> 10;          // 0=Q 1=K 2=V (constant per thread)
  const int rem   = c0 & 1023;
  const int h     = rem >> 6;
  const int d0    = rem & 63;
  float bj[4] = {bias[c0], bias[c0 + 1], bias[c0 + 2], bias[c0 + 3]};
  const int rbase = row0 + ty * 4;
  const int b  = rbase >> 11;          // same for all 4 rows (64-aligned tile)
  const int t0 = rbase & 2047;
  const int bh = b * NH + h;

  if (which == 2) {
    // Vt[bh][d][t]: pack 4 consecutive t per store
#pragma unroll
    for (int j = 0; j < 4; ++j) {
      ushort4 pk;
      pk.x = f2bf(acc[0][j] + bj[j]);
      pk.y = f2bf(acc[1][j] + bj[j]);
      pk.z = f2bf(acc[2][j] + bj[j]);
      pk.w = f2bf(acc[3][j] + bj[j]);
      *(ushort4*)&Vtb[((size_t)bh * HD + d0 + j) * SEQ + t0] = pk;
    }
  } else {
    unsigned short* dst = (which == 0) ? Qb : Kb;
#pragma unroll
    for (int i = 0; i < 4; ++i) {
      ushort4 pk;
      pk.x = f2bf(acc[i][0] + bj[0]);
      pk.y = f2bf(acc[i][1] + bj[1]);
      pk.z = f2bf(acc[i][2] + bj[2]);
      pk.w = f2bf(acc[i][3] + bj[3]);
      *(ushort4*)&dst[((size_t)bh * SEQ + t0 + i) * HD + d0] = pk;
    }
  }
}

// ---------------------------------------------------------------------------
// Kernel 2: MFMA flash attention (bf16 in, fp32 accum).
// Block = 256 thr = 4 waves, covers 64 q rows of one (b,h); wave w owns 16
// q rows. K-tile = 64 keys staged in LDS (stride PADW). 16x16x32 bf16 MFMA,
// verified layouts: C/D col=lane&15 row=quad*4+reg; A[m=lane&15][k=quad*8+j].
// ---------------------------------------------------------------------------
__global__ __launch_bounds__(256) void flash_mfma(
    const unsigned short* __restrict__ Qb, const unsigned short* __restrict__ Kb,
    const unsigned short* __restrict__ Vtb, float* __restrict__ A) {
  const int blk   = blockIdx.x;        // 0..1023
  const int chunk = blk & 31;          // causal load-balance interleave
  const int bh    = blk >> 5;          // 0..31
  const int q0    = chunk * 64;
  const int tid   = threadIdx.x;
  const int lane  = tid & 63;
  const int wave  = tid >> 6;          // 0..3
  const int col   = lane & 15;
  const int quad  = lane >> 4;

  __shared__ unsigned short Ks[64 * PADW];
  __shared__ unsigned short Vts[64 * PADW];
  __shared__ unsigned short Ps[4][16 * PADW];

  const int qw = q0 + wave * 16;       // wave's q base

  // Q A-frags (row-major [t][d], lane m=col, k=quad*8+j): two 16B loads
  const unsigned short* qptr = Qb + ((size_t)bh * SEQ + qw + col) * HD;
  bfrag qa0 = *(const bfrag*)(qptr + quad * 8);
  bfrag qa1 = *(const bfrag*)(qptr + 32 + quad * 8);

  f32x4 o[4];
  float m_r[4], l_r[4];
#pragma unroll
  for (int r = 0; r < 4; ++r) { m_r[r] = -3.0e38f; l_r[r] = 0.f; }
#pragma unroll
  for (int n = 0; n < 4; ++n) o[n] = (f32x4){0.f, 0.f, 0.f, 0.f};

  const size_t kbase  = (size_t)bh * SEQ * HD;
  const size_t vtbase = (size_t)bh * HD * SEQ;
  const int ntiles = q0 / 64 + 1;      // same for all 4 waves -> barrier-safe

  for (int t = 0; t < ntiles; ++t) {
    const int k0 = t * 64;
    __syncthreads();
    // stage K[64][64] and Vt[64][64] (bf16): 512 x 16B each, 2 per thread
    {
      int f = tid;
#pragma unroll
      for (int it = 0; it < 2; ++it, f += 256) {
        int r  = f >> 3;
        int c8 = (f & 7) * 8;
        *(bfrag*)&Ks[r * PADW + c8] =
            *(const bfrag*)(Kb + kbase + (size_t)(k0 + r) * HD + c8);
        *(bfrag*)&Vts[r * PADW + c8] =
            *(const bfrag*)(Vtb + vtbase + (size_t)r * SEQ + k0 + c8);
      }
    }
    __syncthreads();

    // S = Q K^T  (4 key-groups of 16)
    f32x4 s[4];
#pragma unroll
    for (int kg = 0; kg < 4; ++kg) {
      const unsigned short* kr = &Ks[(kg * 16 + col) * PADW];
      bfrag kb0 = *(const bfrag*)(kr + quad * 8);
      bfrag kb1 = *(const bfrag*)(kr + 32 + quad * 8);
      f32x4 c = (f32x4){0.f, 0.f, 0.f, 0.f};
      c = __builtin_amdgcn_mfma_f32_16x16x32_bf16(qa0, kb0, c, 0, 0, 0);
      c = __builtin_amdgcn_mfma_f32_16x16x32_bf16(qa1, kb1, c, 0, 0, 0);
      s[kg] = c;
    }

    // online softmax (per C-row q = qw + quad*4 + r)
    float mnew[4], alpha[4];
#pragma unroll
    for (int r = 0; r < 4; ++r) {
      const int qg = qw + quad * 4 + r;
      float mx = m_r[r];
#pragma unroll
      for (int kg = 0; kg < 4; ++kg) {
        float v = s[kg][r] * 0.125f;
        int keyg = k0 + kg * 16 + col;
        if (keyg > qg) v = -3.0e38f;
        s[kg][r] = v;
        mx = fmaxf(mx, v);
      }
      mx = fmaxf(mx, __shfl_xor(mx, 1));
      mx = fmaxf(mx, __shfl_xor(mx, 2));
      mx = fmaxf(mx, __shfl_xor(mx, 4));
      mx = fmaxf(mx, __shfl_xor(mx, 8));
      mnew[r]  = mx;
      alpha[r] = __expf(m_r[r] - mx);
      m_r[r]   = mx;
    }
#pragma unroll
    for (int r = 0; r < 4; ++r) {
      float lsum = 0.f;
#pragma unroll
      for (int kg = 0; kg < 4; ++kg) {
        float v = s[kg][r];
        float p = __expf(v - mnew[r]);
        if (v < -1.0e37f) p = 0.f;   // guard: all-masked / -inf row state
        s[kg][r] = p;
        lsum += p;
      }
      lsum += __shfl_xor(lsum, 1);
      lsum += __shfl_xor(lsum, 2);
      lsum += __shfl_xor(lsum, 4);
      lsum += __shfl_xor(lsum, 8);
      l_r[r] = l_r[r] * alpha[r] + lsum;
      o[0][r] *= alpha[r]; o[1][r] *= alpha[r];
      o[2][r] *= alpha[r]; o[3][r] *= alpha[r];
    }

    // P: C-layout -> bf16 -> per-wave LDS -> A-layout frags (m120 pattern)
    unsigned short* pw = Ps[wave];
#pragma unroll
    for (int kg = 0; kg < 4; ++kg)
#pragma unroll
      for (int r = 0; r < 4; ++r)
        pw[(quad * 4 + r) * PADW + kg * 16 + col] = f2bf(s[kg][r]);
    __asm__ volatile("s_waitcnt lgkmcnt(0)" ::: "memory");
    bfrag pa0 = *(const bfrag*)&pw[col * PADW + quad * 8];
    bfrag pa1 = *(const bfrag*)&pw[col * PADW + 32 + quad * 8];

    // O += P V   (B-frag from Vt[d][key]: contiguous 16B per lane)
#pragma unroll
    for (int n = 0; n < 4; ++n) {
      const unsigned short* vr = &Vts[(n * 16 + col) * PADW];
      bfrag vb0 = *(const bfrag*)(vr + quad * 8);
      bfrag vb1 = *(const bfrag*)(vr + 32 + quad * 8);
      o[n] = __builtin_amdgcn_mfma_f32_16x16x32_bf16(pa0, vb0, o[n], 0, 0, 0);
      o[n] = __builtin_amdgcn_mfma_f32_16x16x32_bf16(pa1, vb1, o[n], 0, 0, 0);
    }
  }

  // epilogue: A[b][t][h*64 + d] fp32
  const int b = bh >> 4, h = bh & 15;
#pragma unroll
  for (int r = 0; r < 4; ++r) {
    const int qg = qw + quad * 4 + r;
    const float inv = 1.0f / l_r[r];
    float* dst = A + ((size_t)b * SEQ + qg) * DIM + h * HD;
#pragma unroll
    for (int n = 0; n < 4; ++n)
      dst[n * 16 + col] = o[n][r] * inv;
  }
}

// ---------------------------------------------------------------------------
// Kernel 3: out = A @ W_proj + b_proj. M=4096, N=1024, K=1024. fp32.
// ---------------------------------------------------------------------------
__global__ __launch_bounds__(256) void proj_gemm(
    const float* __restrict__ A, const float* __restrict__ W,
    const float* __restrict__ bias, float* __restrict__ out) {
  const int bn = blockIdx.x;
  const int bm = blockIdx.y;
  const int tid = threadIdx.x;
  const int tx = tid & 15;
  const int ty = tid >> 4;
  const int row0 = bm * 64, col0 = bn * 64;

  __shared__ float As[16][68];
  __shared__ float Bs[16][68];

  float acc[4][4] = {};

  for (int k0 = 0; k0 < DIM; k0 += 16) {
    {
      int m  = tid >> 2;
      int kk = (tid & 3) * 4;
      float4 v = *(const float4*)(A + (size_t)(row0 + m) * DIM + k0 + kk);
      As[kk + 0][m] = v.x; As[kk + 1][m] = v.y;
      As[kk + 2][m] = v.z; As[kk + 3][m] = v.w;
    }
    {
      int kk = tid >> 4;
      int n  = (tid & 15) * 4;
      float4 v = *(const float4*)(W + (size_t)(k0 + kk) * DIM + col0 + n);
      *(float4*)&Bs[kk][n] = v;
    }
    __syncthreads();
#pragma unroll
    for (int kk = 0; kk < 16; ++kk) {
      float4 av = *(const float4*)&As[kk][ty * 4];
      float4 bv = *(const float4*)&Bs[kk][tx * 4];
      float a[4] = {av.x, av.y, av.z, av.w};
      float b[4] = {bv.x, bv.y, bv.z, bv.w};
#pragma unroll
      for (int i = 0; i < 4; ++i)
#pragma unroll
        for (int j = 0; j < 4; ++j) acc[i][j] += a[i] * b[j];
    }
    __syncthreads();
  }

#pragma unroll
  for (int i = 0; i < 4; ++i) {
    int r = row0 + ty * 4 + i;
#pragma unroll
    for (int j = 0; j < 4; ++j) {
      int c = col0 + tx * 4 + j;
      out[(size_t)r * DIM + c] = acc[i][j] + bias[c];
    }
  }
}

// ---------------------------------------------------------------------------
extern "C" void kernel_launch(void* const* d_in, const int* in_sizes, int n_in,
                              void* d_out, int out_size, void* d_ws, size_t ws_size,
                              hipStream_t stream) {
  const float* x      = (const float*)d_in[0];
  const float* W_qkv  = (const float*)d_in[1];
  const float* b_qkv  = (const float*)d_in[2];
  const float* W_proj = (const float*)d_in[3];
  const float* b_proj = (const float*)d_in[4];
  float* out = (float*)d_out;

  const size_t qkv_elems = (size_t)BATCH * NH * SEQ * HD;  // 4M
  unsigned short* Qb  = (unsigned short*)d_ws;
  unsigned short* Kb  = Qb + qkv_elems;
  unsigned short* Vtb = Kb + qkv_elems;
  float* A = (float*)(Vtb + qkv_elems);                    // [B,T,C] fp32

  dim3 g1(3072 / 64, NROWS / 64);
  qkv_gemm<<<g1, 256, 0, stream>>>(x, W_qkv, b_qkv, Qb, Kb, Vtb);

  flash_mfma<<<dim3(BATCH * NH * (SEQ / 64)), 256, 0, stream>>>(Qb, Kb, Vtb, A);

  dim3 g3(DIM / 64, NROWS / 64);
  proj_gemm<<<g3, 256, 0, stream>>>(A, W_proj, b_proj, out);
}

// Round 3
// 286.597 us; speedup vs baseline: 9.3115x; 2.4200x over previous
//
#include <hip/hip_runtime.h>
#include <hip/hip_bf16.h>
#include <cstddef>
#include <cstdint>

#define DIM   1024
#define NH    16
#define HD    64
#define BATCH 2
#define SEQ   2048
#define NROWS (BATCH * SEQ)   // 4096
#define PADW  72              // flash LDS row stride in ushorts

typedef __bf16 bfrag  __attribute__((ext_vector_type(8)));
typedef float  f32x4  __attribute__((ext_vector_type(4)));

__device__ __forceinline__ unsigned short f2bf(float f) {
  union { float f; uint32_t u; } v; v.f = f;
  uint32_t r = (v.u + 0x7FFF + ((v.u >> 16) & 1)) >> 16;
  return (unsigned short)r;
}

__device__ __forceinline__ void async_copy16(const unsigned short* g,
                                             unsigned short* l) {
  __builtin_amdgcn_global_load_lds(
      (const __attribute__((address_space(1))) unsigned int*)g,
      (__attribute__((address_space(3))) unsigned int*)l, 16, 0, 0);
}

// ---------------------------------------------------------------------------
// Prep: x fp32 -> bf16 (same layout)
// ---------------------------------------------------------------------------
__global__ __launch_bounds__(256) void cvt_x(const float* __restrict__ x,
                                             unsigned short* __restrict__ xb) {
  int i = (blockIdx.x * 256 + threadIdx.x) * 4;
  float4 v = *(const float4*)(x + i);
  ushort4 p = {f2bf(v.x), f2bf(v.y), f2bf(v.z), f2bf(v.w)};
  *(ushort4*)(xb + i) = p;
}

// ---------------------------------------------------------------------------
// Prep: W [R][C] fp32 -> Wt [C][R] bf16 (transpose-convert, 32x32 LDS tile)
// ---------------------------------------------------------------------------
__global__ __launch_bounds__(256) void cvt_t(const float* __restrict__ src,
                                             unsigned short* __restrict__ dst,
                                             int R, int C) {
  __shared__ float t[32][33];
  const int r0 = blockIdx.y * 32, c0 = blockIdx.x * 32;
  const int tx = threadIdx.x, ty = threadIdx.y;
#pragma unroll
  for (int i = 0; i < 4; ++i)
    t[ty + i * 8][tx] = src[(size_t)(r0 + ty + i * 8) * C + c0 + tx];
  __syncthreads();
#pragma unroll
  for (int i = 0; i < 4; ++i)
    dst[(size_t)(c0 + ty + i * 8) * R + r0 + tx] = f2bf(t[tx][ty + i * 8]);
}

// ---------------------------------------------------------------------------
// Kernel 1: qkv = x_bf @ Wt_qkv^T + b -> bf16 Q[bh][t][d], K[bh][t][d],
// Vt[bh][d][t].  m97 structure: 128x128 tile, BK=32, 4 waves, 16x16x32 MFMA,
// global_load_lds width-16 staging into unpadded LDS.
// ---------------------------------------------------------------------------
__global__ __launch_bounds__(256) void qkv_mfma(
    const unsigned short* __restrict__ Ax,   // [4096][1024] bf16
    const unsigned short* __restrict__ Bt,   // [3072][1024] bf16 (W^T)
    const float* __restrict__ bias,
    unsigned short* __restrict__ Qb, unsigned short* __restrict__ Kb,
    unsigned short* __restrict__ Vtb) {
  const int row0 = blockIdx.y * 128;         // 0..31 tiles
  const int col0 = blockIdx.x * 128;         // 0..23 tiles
  const int tid  = threadIdx.x;
  const int lane = tid & 63;
  const int wave = tid >> 6;
  const int col  = lane & 15;
  const int quad = lane >> 4;
  const int wm = wave >> 1, wn = wave & 1;   // 2x2 wave grid, 64x64 each

  __shared__ unsigned short As[128 * 32];
  __shared__ unsigned short Bs[128 * 32];

  f32x4 acc[4][4];
#pragma unroll
  for (int i = 0; i < 4; ++i)
#pragma unroll
    for (int j = 0; j < 4; ++j) acc[i][j] = (f32x4){0.f, 0.f, 0.f, 0.f};

  for (int k0 = 0; k0 < DIM; k0 += 32) {
    __syncthreads();
#pragma unroll
    for (int it = 0; it < 2; ++it) {
      int c = tid + it * 256;                // 0..511 16B-chunks
      int r = c >> 2, o8 = (c & 3) * 8;
      async_copy16(Ax + (size_t)(row0 + r) * DIM + k0 + o8, &As[c * 8]);
      async_copy16(Bt + (size_t)(col0 + r) * DIM + k0 + o8, &Bs[c * 8]);
    }
    __syncthreads();

    bfrag a[4], b[4];
#pragma unroll
    for (int i = 0; i < 4; ++i)
      a[i] = *(const bfrag*)&As[(wm * 64 + i * 16 + col) * 32 + quad * 8];
#pragma unroll
    for (int j = 0; j < 4; ++j)
      b[j] = *(const bfrag*)&Bs[(wn * 64 + j * 16 + col) * 32 + quad * 8];
#pragma unroll
    for (int i = 0; i < 4; ++i)
#pragma unroll
      for (int j = 0; j < 4; ++j)
        acc[i][j] = __builtin_amdgcn_mfma_f32_16x16x32_bf16(a[i], b[j],
                                                            acc[i][j], 0, 0, 0);
  }

  // Epilogue. which (Q/K/V) uniform per block: 128 | 1024.
  const int which = col0 >> 10;
  float bj[4];
#pragma unroll
  for (int j = 0; j < 4; ++j) bj[j] = bias[col0 + wn * 64 + j * 16 + col];

#pragma unroll
  for (int i = 0; i < 4; ++i) {
#pragma unroll
    for (int r = 0; r < 4; ++r) {
      const int row = row0 + wm * 64 + i * 16 + quad * 4 + r;
      const int bb = row >> 11, tt = row & 2047;
#pragma unroll
      for (int j = 0; j < 4; ++j) {
        const int cg = col0 + wn * 64 + j * 16 + col;
        const int rem = cg & 1023;
        const int h = rem >> 6, d = rem & 63;
        const int bh = bb * NH + h;
        unsigned short val = f2bf(acc[i][j][r] + bj[j]);
        if (which == 2)
          Vtb[((size_t)bh * HD + d) * SEQ + tt] = val;
        else if (which == 0)
          Qb[((size_t)bh * SEQ + tt) * HD + d] = val;
        else
          Kb[((size_t)bh * SEQ + tt) * HD + d] = val;
      }
    }
  }
}

// ---------------------------------------------------------------------------
// Kernel 2: MFMA flash attention (bf16 in, fp32 accum), unchanged except
// epilogue now emits bf16 A for the MFMA projection.
// ---------------------------------------------------------------------------
__global__ __launch_bounds__(256) void flash_mfma(
    const unsigned short* __restrict__ Qb, const unsigned short* __restrict__ Kb,
    const unsigned short* __restrict__ Vtb, unsigned short* __restrict__ Abf) {
  const int blk   = blockIdx.x;
  const int chunk = blk & 31;
  const int bh    = blk >> 5;
  const int q0    = chunk * 64;
  const int tid   = threadIdx.x;
  const int lane  = tid & 63;
  const int wave  = tid >> 6;
  const int col   = lane & 15;
  const int quad  = lane >> 4;

  __shared__ unsigned short Ks[64 * PADW];
  __shared__ unsigned short Vts[64 * PADW];
  __shared__ unsigned short Ps[4][16 * PADW];

  const int qw = q0 + wave * 16;

  const unsigned short* qptr = Qb + ((size_t)bh * SEQ + qw + col) * HD;
  bfrag qa0 = *(const bfrag*)(qptr + quad * 8);
  bfrag qa1 = *(const bfrag*)(qptr + 32 + quad * 8);

  f32x4 o[4];
  float m_r[4], l_r[4];
#pragma unroll
  for (int r = 0; r < 4; ++r) { m_r[r] = -3.0e38f; l_r[r] = 0.f; }
#pragma unroll
  for (int n = 0; n < 4; ++n) o[n] = (f32x4){0.f, 0.f, 0.f, 0.f};

  const size_t kbase  = (size_t)bh * SEQ * HD;
  const size_t vtbase = (size_t)bh * HD * SEQ;
  const int ntiles = q0 / 64 + 1;

  for (int t = 0; t < ntiles; ++t) {
    const int k0 = t * 64;
    __syncthreads();
    {
      int f = tid;
#pragma unroll
      for (int it = 0; it < 2; ++it, f += 256) {
        int r  = f >> 3;
        int c8 = (f & 7) * 8;
        *(bfrag*)&Ks[r * PADW + c8] =
            *(const bfrag*)(Kb + kbase + (size_t)(k0 + r) * HD + c8);
        *(bfrag*)&Vts[r * PADW + c8] =
            *(const bfrag*)(Vtb + vtbase + (size_t)r * SEQ + k0 + c8);
      }
    }
    __syncthreads();

    f32x4 s[4];
#pragma unroll
    for (int kg = 0; kg < 4; ++kg) {
      const unsigned short* kr = &Ks[(kg * 16 + col) * PADW];
      bfrag kb0 = *(const bfrag*)(kr + quad * 8);
      bfrag kb1 = *(const bfrag*)(kr + 32 + quad * 8);
      f32x4 c = (f32x4){0.f, 0.f, 0.f, 0.f};
      c = __builtin_amdgcn_mfma_f32_16x16x32_bf16(qa0, kb0, c, 0, 0, 0);
      c = __builtin_amdgcn_mfma_f32_16x16x32_bf16(qa1, kb1, c, 0, 0, 0);
      s[kg] = c;
    }

    float mnew[4], alpha[4];
#pragma unroll
    for (int r = 0; r < 4; ++r) {
      const int qg = qw + quad * 4 + r;
      float mx = m_r[r];
#pragma unroll
      for (int kg = 0; kg < 4; ++kg) {
        float v = s[kg][r] * 0.125f;
        int keyg = k0 + kg * 16 + col;
        if (keyg > qg) v = -3.0e38f;
        s[kg][r] = v;
        mx = fmaxf(mx, v);
      }
      mx = fmaxf(mx, __shfl_xor(mx, 1));
      mx = fmaxf(mx, __shfl_xor(mx, 2));
      mx = fmaxf(mx, __shfl_xor(mx, 4));
      mx = fmaxf(mx, __shfl_xor(mx, 8));
      mnew[r]  = mx;
      alpha[r] = __expf(m_r[r] - mx);
      m_r[r]   = mx;
    }
#pragma unroll
    for (int r = 0; r < 4; ++r) {
      float lsum = 0.f;
#pragma unroll
      for (int kg = 0; kg < 4; ++kg) {
        float v = s[kg][r];
        float p = __expf(v - mnew[r]);
        if (v < -1.0e37f) p = 0.f;
        s[kg][r] = p;
        lsum += p;
      }
      lsum += __shfl_xor(lsum, 1);
      lsum += __shfl_xor(lsum, 2);
      lsum += __shfl_xor(lsum, 4);
      lsum += __shfl_xor(lsum, 8);
      l_r[r] = l_r[r] * alpha[r] + lsum;
      o[0][r] *= alpha[r]; o[1][r] *= alpha[r];
      o[2][r] *= alpha[r]; o[3][r] *= alpha[r];
    }

    unsigned short* pw = Ps[wave];
#pragma unroll
    for (int kg = 0; kg < 4; ++kg)
#pragma unroll
      for (int r = 0; r < 4; ++r)
        pw[(quad * 4 + r) * PADW + kg * 16 + col] = f2bf(s[kg][r]);
    __asm__ volatile("s_waitcnt lgkmcnt(0)" ::: "memory");
    bfrag pa0 = *(const bfrag*)&pw[col * PADW + quad * 8];
    bfrag pa1 = *(const bfrag*)&pw[col * PADW + 32 + quad * 8];

#pragma unroll
    for (int n = 0; n < 4; ++n) {
      const unsigned short* vr = &Vts[(n * 16 + col) * PADW];
      bfrag vb0 = *(const bfrag*)(vr + quad * 8);
      bfrag vb1 = *(const bfrag*)(vr + 32 + quad * 8);
      o[n] = __builtin_amdgcn_mfma_f32_16x16x32_bf16(pa0, vb0, o[n], 0, 0, 0);
      o[n] = __builtin_amdgcn_mfma_f32_16x16x32_bf16(pa1, vb1, o[n], 0, 0, 0);
    }
  }

  const int b = bh >> 4, h = bh & 15;
#pragma unroll
  for (int r = 0; r < 4; ++r) {
    const int qg = qw + quad * 4 + r;
    const float inv = 1.0f / l_r[r];
    unsigned short* dst = Abf + ((size_t)b * SEQ + qg) * DIM + h * HD;
#pragma unroll
    for (int n = 0; n < 4; ++n)
      dst[n * 16 + col] = f2bf(o[n][r] * inv);
  }
}

// ---------------------------------------------------------------------------
// Kernel 3: out = Abf @ Wt_proj^T + b_proj (fp32 out). Same m97 structure.
// ---------------------------------------------------------------------------
__global__ __launch_bounds__(256) void proj_mfma(
    const unsigned short* __restrict__ Ax,   // [4096][1024] bf16
    const unsigned short* __restrict__ Bt,   // [1024][1024] bf16 (W^T)
    const float* __restrict__ bias, float* __restrict__ out) {
  const int row0 = blockIdx.y * 128;
  const int col0 = blockIdx.x * 128;
  const int tid  = threadIdx.x;
  const int lane = tid & 63;
  const int wave = tid >> 6;
  const int col  = lane & 15;
  const int quad = lane >> 4;
  const int wm = wave >> 1, wn = wave & 1;

  __shared__ unsigned short As[128 * 32];
  __shared__ unsigned short Bs[128 * 32];

  f32x4 acc[4][4];
#pragma unroll
  for (int i = 0; i < 4; ++i)
#pragma unroll
    for (int j = 0; j < 4; ++j) acc[i][j] = (f32x4){0.f, 0.f, 0.f, 0.f};

  for (int k0 = 0; k0 < DIM; k0 += 32) {
    __syncthreads();
#pragma unroll
    for (int it = 0; it < 2; ++it) {
      int c = tid + it * 256;
      int r = c >> 2, o8 = (c & 3) * 8;
      async_copy16(Ax + (size_t)(row0 + r) * DIM + k0 + o8, &As[c * 8]);
      async_copy16(Bt + (size_t)(col0 + r) * DIM + k0 + o8, &Bs[c * 8]);
    }
    __syncthreads();

    bfrag a[4], b[4];
#pragma unroll
    for (int i = 0; i < 4; ++i)
      a[i] = *(const bfrag*)&As[(wm * 64 + i * 16 + col) * 32 + quad * 8];
#pragma unroll
    for (int j = 0; j < 4; ++j)
      b[j] = *(const bfrag*)&Bs[(wn * 64 + j * 16 + col) * 32 + quad * 8];
#pragma unroll
    for (int i = 0; i < 4; ++i)
#pragma unroll
      for (int j = 0; j < 4; ++j)
        acc[i][j] = __builtin_amdgcn_mfma_f32_16x16x32_bf16(a[i], b[j],
                                                            acc[i][j], 0, 0, 0);
  }

  float bj[4];
#pragma unroll
  for (int j = 0; j < 4; ++j) bj[j] = bias[col0 + wn * 64 + j * 16 + col];

#pragma unroll
  for (int i = 0; i < 4; ++i)
#pragma unroll
    for (int r = 0; r < 4; ++r) {
      const int row = row0 + wm * 64 + i * 16 + quad * 4 + r;
#pragma unroll
      for (int j = 0; j < 4; ++j) {
        const int cg = col0 + wn * 64 + j * 16 + col;
        out[(size_t)row * DIM + cg] = acc[i][j][r] + bj[j];
      }
    }
}

// ---------------------------------------------------------------------------
extern "C" void kernel_launch(void* const* d_in, const int* in_sizes, int n_in,
                              void* d_out, int out_size, void* d_ws, size_t ws_size,
                              hipStream_t stream) {
  const float* x      = (const float*)d_in[0];
  const float* W_qkv  = (const float*)d_in[1];
  const float* b_qkv  = (const float*)d_in[2];
  const float* W_proj = (const float*)d_in[3];
  const float* b_proj = (const float*)d_in[4];
  float* out = (float*)d_out;

  const size_t qkv_elems = (size_t)BATCH * NH * SEQ * HD;  // 4M
  unsigned short* Qb  = (unsigned short*)d_ws;
  unsigned short* Kb  = Qb + qkv_elems;
  unsigned short* Vtb = Kb + qkv_elems;
  unsigned short* Abf = Vtb + qkv_elems;                   // [B,T,C] bf16
  unsigned short* xb  = Abf + qkv_elems;                   // [4096][1024]
  unsigned short* Wtq = xb + (size_t)NROWS * DIM;          // [3072][1024]
  unsigned short* Wtp = Wtq + (size_t)3072 * DIM;          // [1024][1024]

  cvt_x<<<dim3(NROWS * DIM / 1024), 256, 0, stream>>>(x, xb);
  cvt_t<<<dim3(3072 / 32, DIM / 32), dim3(32, 8), 0, stream>>>(W_qkv, Wtq,
                                                               DIM, 3072);
  cvt_t<<<dim3(DIM / 32, DIM / 32), dim3(32, 8), 0, stream>>>(W_proj, Wtp,
                                                              DIM, DIM);

  qkv_mfma<<<dim3(3072 / 128, NROWS / 128), 256, 0, stream>>>(
      xb, Wtq, b_qkv, Qb, Kb, Vtb);

  flash_mfma<<<dim3(BATCH * NH * (SEQ / 64)), 256, 0, stream>>>(Qb, Kb, Vtb,
                                                                Abf);

  proj_mfma<<<dim3(DIM / 128, NROWS / 128), 256, 0, stream>>>(
      Abf, Wtp, b_proj, out);
}

// Round 4
// 282.279 us; speedup vs baseline: 9.4539x; 1.0153x over previous
//
#include <hip/hip_runtime.h>
#include <hip/hip_bf16.h>
#include <cstddef>
#include <cstdint>

#define DIM   1024
#define NH    16
#define HD    64
#define BATCH 2
#define SEQ   2048
#define NROWS (BATCH * SEQ)   // 4096
#define PADW  72              // flash LDS row stride in ushorts (144B)
#define QSCALE 0.1803368801111204f   // 0.125 * log2(e): softmax in exp2 domain

typedef __bf16 bfrag  __attribute__((ext_vector_type(8)));
typedef float  f32x4  __attribute__((ext_vector_type(4)));

__device__ __forceinline__ unsigned short f2bf(float f) {
  union { float f; uint32_t u; } v; v.f = f;
  uint32_t r = (v.u + 0x7FFF + ((v.u >> 16) & 1)) >> 16;
  return (unsigned short)r;
}

__device__ __forceinline__ void async_copy16(const unsigned short* g,
                                             unsigned short* l) {
  __builtin_amdgcn_global_load_lds(
      (const __attribute__((address_space(1))) unsigned int*)g,
      (__attribute__((address_space(3))) unsigned int*)l, 16, 0, 0);
}

// ---------------------------------------------------------------------------
// Prep: x fp32 -> bf16
// ---------------------------------------------------------------------------
__global__ __launch_bounds__(256) void cvt_x(const float* __restrict__ x,
                                             unsigned short* __restrict__ xb) {
  int i = (blockIdx.x * 256 + threadIdx.x) * 4;
  float4 v = *(const float4*)(x + i);
  ushort4 p = {f2bf(v.x), f2bf(v.y), f2bf(v.z), f2bf(v.w)};
  *(ushort4*)(xb + i) = p;
}

// ---------------------------------------------------------------------------
// Prep: W [R][C] fp32 -> Wt [C][R] bf16 (transpose-convert)
// ---------------------------------------------------------------------------
__global__ __launch_bounds__(256) void cvt_t(const float* __restrict__ src,
                                             unsigned short* __restrict__ dst,
                                             int R, int C) {
  __shared__ float t[32][33];
  const int r0 = blockIdx.y * 32, c0 = blockIdx.x * 32;
  const int tx = threadIdx.x, ty = threadIdx.y;
#pragma unroll
  for (int i = 0; i < 4; ++i)
    t[ty + i * 8][tx] = src[(size_t)(r0 + ty + i * 8) * C + c0 + tx];
  __syncthreads();
#pragma unroll
  for (int i = 0; i < 4; ++i)
    dst[(size_t)(c0 + ty + i * 8) * R + r0 + tx] = f2bf(t[tx][ty + i * 8]);
}

// ---------------------------------------------------------------------------
// Kernel 1: qkv = x_bf @ Wt_qkv^T + b -> bf16 Q (pre-scaled by 0.125*log2e),
// K [bh][t][d], Vt [bh][d][t]. m97 structure.
// ---------------------------------------------------------------------------
__global__ __launch_bounds__(256) void qkv_mfma(
    const unsigned short* __restrict__ Ax,   // [4096][1024] bf16
    const unsigned short* __restrict__ Bt,   // [3072][1024] bf16 (W^T)
    const float* __restrict__ bias,
    unsigned short* __restrict__ Qb, unsigned short* __restrict__ Kb,
    unsigned short* __restrict__ Vtb) {
  const int row0 = blockIdx.y * 128;
  const int col0 = blockIdx.x * 128;
  const int tid  = threadIdx.x;
  const int lane = tid & 63;
  const int wave = tid >> 6;
  const int col  = lane & 15;
  const int quad = lane >> 4;
  const int wm = wave >> 1, wn = wave & 1;

  __shared__ unsigned short As[128 * 32];
  __shared__ unsigned short Bs[128 * 32];

  f32x4 acc[4][4];
#pragma unroll
  for (int i = 0; i < 4; ++i)
#pragma unroll
    for (int j = 0; j < 4; ++j) acc[i][j] = (f32x4){0.f, 0.f, 0.f, 0.f};

  for (int k0 = 0; k0 < DIM; k0 += 32) {
    __syncthreads();
#pragma unroll
    for (int it = 0; it < 2; ++it) {
      int c = tid + it * 256;
      int r = c >> 2, o8 = (c & 3) * 8;
      async_copy16(Ax + (size_t)(row0 + r) * DIM + k0 + o8, &As[c * 8]);
      async_copy16(Bt + (size_t)(col0 + r) * DIM + k0 + o8, &Bs[c * 8]);
    }
    __syncthreads();

    bfrag a[4], b[4];
#pragma unroll
    for (int i = 0; i < 4; ++i)
      a[i] = *(const bfrag*)&As[(wm * 64 + i * 16 + col) * 32 + quad * 8];
#pragma unroll
    for (int j = 0; j < 4; ++j)
      b[j] = *(const bfrag*)&Bs[(wn * 64 + j * 16 + col) * 32 + quad * 8];
#pragma unroll
    for (int i = 0; i < 4; ++i)
#pragma unroll
      for (int j = 0; j < 4; ++j)
        acc[i][j] = __builtin_amdgcn_mfma_f32_16x16x32_bf16(a[i], b[j],
                                                            acc[i][j], 0, 0, 0);
  }

  const int which = col0 >> 10;        // 0=Q 1=K 2=V, block-uniform
  float bj[4];
#pragma unroll
  for (int j = 0; j < 4; ++j) bj[j] = bias[col0 + wn * 64 + j * 16 + col];

#pragma unroll
  for (int i = 0; i < 4; ++i) {
#pragma unroll
    for (int r = 0; r < 4; ++r) {
      const int row = row0 + wm * 64 + i * 16 + quad * 4 + r;
      const int bb = row >> 11, tt = row & 2047;
#pragma unroll
      for (int j = 0; j < 4; ++j) {
        const int cg = col0 + wn * 64 + j * 16 + col;
        const int rem = cg & 1023;
        const int h = rem >> 6, d = rem & 63;
        const int bh = bb * NH + h;
        float v = acc[i][j][r] + bj[j];
        if (which == 0) v *= QSCALE;   // fold softmax scale+log2e into Q
        unsigned short val = f2bf(v);
        if (which == 2)
          Vtb[((size_t)bh * HD + d) * SEQ + tt] = val;
        else if (which == 0)
          Qb[((size_t)bh * SEQ + tt) * HD + d] = val;
        else
          Kb[((size_t)bh * SEQ + tt) * HD + d] = val;
      }
    }
  }
}

// ---------------------------------------------------------------------------
// Kernel 2: MFMA flash attention, S^T formulation.
// S^T = K Q^T  (C-layout: col=q, row=key). K rows staged into LDS in
// permuted order pi(m) = quad*8 + (kg&1)*4 + r + (kg&2)*16 so the lane's
// 4 S^T fragments concatenate directly into the PV A-operand (k=quad*8+j).
// Softmax is lane-local (one q per lane) + 2 cross-quad shuffles.
// Scores arrive pre-scaled into the exp2 domain (Q carries 0.125*log2e).
// ---------------------------------------------------------------------------
__global__ __launch_bounds__(256) void flash_mfma(
    const unsigned short* __restrict__ Qb, const unsigned short* __restrict__ Kb,
    const unsigned short* __restrict__ Vtb, unsigned short* __restrict__ Abf) {
  const int blk   = blockIdx.x;
  const int chunk = blk & 31;          // causal load-balance interleave
  const int bh    = blk >> 5;
  const int q0    = chunk * 64;
  const int tid   = threadIdx.x;
  const int lane  = tid & 63;
  const int wave  = tid >> 6;
  const int col   = lane & 15;
  const int quad  = lane >> 4;

  __shared__ unsigned short Ks[64 * PADW];   // row m = K[k0 + pi(m)]
  __shared__ unsigned short Vts[64 * PADW];  // row d, cols = keys (identity)

  const int qw = q0 + wave * 16;

  // Q as B-operand: B[n=q][k=d], lane n=col, k=quad*8+j
  const unsigned short* qptr = Qb + ((size_t)bh * SEQ + qw + col) * HD;
  bfrag qb0 = *(const bfrag*)(qptr + quad * 8);
  bfrag qb1 = *(const bfrag*)(qptr + 32 + quad * 8);

  f32x4 o[4];
#pragma unroll
  for (int n = 0; n < 4; ++n) o[n] = (f32x4){0.f, 0.f, 0.f, 0.f};
  float m_s = -3.0e38f, l_s = 0.f;     // state for q = qw + col

  const size_t kbase  = (size_t)bh * SEQ * HD;
  const size_t vtbase = (size_t)bh * HD * SEQ;
  const int ntiles = q0 / 64 + 1;

  for (int t = 0; t < ntiles; ++t) {
    const int k0 = t * 64;
    __syncthreads();
    {
      int f = tid;
#pragma unroll
      for (int it = 0; it < 2; ++it, f += 256) {
        int r  = f >> 3;
        int c8 = (f & 7) * 8;
        int pr = ((r >> 2) & 3) * 8 + ((r >> 4) & 1) * 4 + (r & 3) + (r & 32);
        *(bfrag*)&Ks[r * PADW + c8] =
            *(const bfrag*)(Kb + kbase + (size_t)(k0 + pr) * HD + c8);
        *(bfrag*)&Vts[r * PADW + c8] =
            *(const bfrag*)(Vtb + vtbase + (size_t)r * SEQ + k0 + c8);
      }
    }
    __syncthreads();

    // S^T = K Q^T : A = K-frag (m=key), B = Q-frag (n=q)
    f32x4 s[4];
#pragma unroll
    for (int kg = 0; kg < 4; ++kg) {
      const unsigned short* kr = &Ks[(kg * 16 + col) * PADW];
      bfrag ka0 = *(const bfrag*)(kr + quad * 8);
      bfrag ka1 = *(const bfrag*)(kr + 32 + quad * 8);
      f32x4 c = (f32x4){0.f, 0.f, 0.f, 0.f};
      c = __builtin_amdgcn_mfma_f32_16x16x32_bf16(ka0, qb0, c, 0, 0, 0);
      c = __builtin_amdgcn_mfma_f32_16x16x32_bf16(ka1, qb1, c, 0, 0, 0);
      s[kg] = c;
    }

    // causal mask: only the diagonal (last) tile needs it
    if (t == ntiles - 1) {
      const int q = qw + col;
#pragma unroll
      for (int kg = 0; kg < 4; ++kg)
#pragma unroll
        for (int r = 0; r < 4; ++r) {
          int key = k0 + quad * 8 + (kg & 1) * 4 + r + (kg & 2) * 16;
          if (key > q) s[kg][r] = -3.0e38f;
        }
    }

    // online softmax (exp2 domain), lane-local + cross-quad shuffles
    float mx = m_s;
#pragma unroll
    for (int kg = 0; kg < 4; ++kg)
#pragma unroll
      for (int r = 0; r < 4; ++r) mx = fmaxf(mx, s[kg][r]);
    mx = fmaxf(mx, __shfl_xor(mx, 16));
    mx = fmaxf(mx, __shfl_xor(mx, 32));
    const float alpha = exp2f(m_s - mx);
    m_s = mx;
    float lsum = 0.f;
#pragma unroll
    for (int kg = 0; kg < 4; ++kg)
#pragma unroll
      for (int r = 0; r < 4; ++r) {
        float p = exp2f(s[kg][r] - mx);
        s[kg][r] = p;
        lsum += p;
      }
    lsum += __shfl_xor(lsum, 16);
    lsum += __shfl_xor(lsum, 32);
    l_s = l_s * alpha + lsum;

    // broadcast alpha into O row layout (row q = quad*4+r) and rescale O
#pragma unroll
    for (int r = 0; r < 4; ++r) {
      float ar = __shfl(alpha, (lane & 48) + quad * 4 + r);
      o[0][r] *= ar; o[1][r] *= ar; o[2][r] *= ar; o[3][r] *= ar;
    }

    // P fragments: direct pack, no cross-lane movement (pi staged it right)
    bfrag pa0, pa1;
#pragma unroll
    for (int r = 0; r < 4; ++r) {
      pa0[r]     = (__bf16)s[0][r];
      pa0[4 + r] = (__bf16)s[1][r];
      pa1[r]     = (__bf16)s[2][r];
      pa1[4 + r] = (__bf16)s[3][r];
    }

    // O += P V : B[n=d][k=key] from Vt rows (identity key order)
#pragma unroll
    for (int n = 0; n < 4; ++n) {
      const unsigned short* vr = &Vts[(n * 16 + col) * PADW];
      bfrag vb0 = *(const bfrag*)(vr + quad * 8);
      bfrag vb1 = *(const bfrag*)(vr + 32 + quad * 8);
      o[n] = __builtin_amdgcn_mfma_f32_16x16x32_bf16(pa0, vb0, o[n], 0, 0, 0);
      o[n] = __builtin_amdgcn_mfma_f32_16x16x32_bf16(pa1, vb1, o[n], 0, 0, 0);
    }
  }

  // epilogue: O row q = qw + quad*4 + r, col d = n*16 + col
  const float linv = 1.0f / l_s;
  const int b = bh >> 4, h = bh & 15;
#pragma unroll
  for (int r = 0; r < 4; ++r) {
    const float lr = __shfl(linv, (lane & 48) + quad * 4 + r);
    unsigned short* dst =
        Abf + ((size_t)b * SEQ + qw + quad * 4 + r) * DIM + h * HD;
#pragma unroll
    for (int n = 0; n < 4; ++n)
      dst[n * 16 + col] = f2bf(o[n][r] * lr);
  }
}

// ---------------------------------------------------------------------------
// Kernel 3: out = Abf @ Wt_proj^T + b_proj (fp32 out). m97 structure.
// ---------------------------------------------------------------------------
__global__ __launch_bounds__(256) void proj_mfma(
    const unsigned short* __restrict__ Ax,
    const unsigned short* __restrict__ Bt,
    const float* __restrict__ bias, float* __restrict__ out) {
  const int row0 = blockIdx.y * 128;
  const int col0 = blockIdx.x * 128;
  const int tid  = threadIdx.x;
  const int lane = tid & 63;
  const int wave = tid >> 6;
  const int col  = lane & 15;
  const int quad = lane >> 4;
  const int wm = wave >> 1, wn = wave & 1;

  __shared__ unsigned short As[128 * 32];
  __shared__ unsigned short Bs[128 * 32];

  f32x4 acc[4][4];
#pragma unroll
  for (int i = 0; i < 4; ++i)
#pragma unroll
    for (int j = 0; j < 4; ++j) acc[i][j] = (f32x4){0.f, 0.f, 0.f, 0.f};

  for (int k0 = 0; k0 < DIM; k0 += 32) {
    __syncthreads();
#pragma unroll
    for (int it = 0; it < 2; ++it) {
      int c = tid + it * 256;
      int r = c >> 2, o8 = (c & 3) * 8;
      async_copy16(Ax + (size_t)(row0 + r) * DIM + k0 + o8, &As[c * 8]);
      async_copy16(Bt + (size_t)(col0 + r) * DIM + k0 + o8, &Bs[c * 8]);
    }
    __syncthreads();

    bfrag a[4], b[4];
#pragma unroll
    for (int i = 0; i < 4; ++i)
      a[i] = *(const bfrag*)&As[(wm * 64 + i * 16 + col) * 32 + quad * 8];
#pragma unroll
    for (int j = 0; j < 4; ++j)
      b[j] = *(const bfrag*)&Bs[(wn * 64 + j * 16 + col) * 32 + quad * 8];
#pragma unroll
    for (int i = 0; i < 4; ++i)
#pragma unroll
      for (int j = 0; j < 4; ++j)
        acc[i][j] = __builtin_amdgcn_mfma_f32_16x16x32_bf16(a[i], b[j],
                                                            acc[i][j], 0, 0, 0);
  }

  float bj[4];
#pragma unroll
  for (int j = 0; j < 4; ++j) bj[j] = bias[col0 + wn * 64 + j * 16 + col];

#pragma unroll
  for (int i = 0; i < 4; ++i)
#pragma unroll
    for (int r = 0; r < 4; ++r) {
      const int row = row0 + wm * 64 + i * 16 + quad * 4 + r;
#pragma unroll
      for (int j = 0; j < 4; ++j) {
        const int cg = col0 + wn * 64 + j * 16 + col;
        out[(size_t)row * DIM + cg] = acc[i][j][r] + bj[j];
      }
    }
}

// ---------------------------------------------------------------------------
extern "C" void kernel_launch(void* const* d_in, const int* in_sizes, int n_in,
                              void* d_out, int out_size, void* d_ws, size_t ws_size,
                              hipStream_t stream) {
  const float* x      = (const float*)d_in[0];
  const float* W_qkv  = (const float*)d_in[1];
  const float* b_qkv  = (const float*)d_in[2];
  const float* W_proj = (const float*)d_in[3];
  const float* b_proj = (const float*)d_in[4];
  float* out = (float*)d_out;

  const size_t qkv_elems = (size_t)BATCH * NH * SEQ * HD;  // 4M
  unsigned short* Qb  = (unsigned short*)d_ws;
  unsigned short* Kb  = Qb + qkv_elems;
  unsigned short* Vtb = Kb + qkv_elems;
  unsigned short* Abf = Vtb + qkv_elems;                   // [B,T,C] bf16
  unsigned short* xb  = Abf + qkv_elems;                   // [4096][1024]
  unsigned short* Wtq = xb + (size_t)NROWS * DIM;          // [3072][1024]
  unsigned short* Wtp = Wtq + (size_t)3072 * DIM;          // [1024][1024]

  cvt_x<<<dim3(NROWS * DIM / 1024), 256, 0, stream>>>(x, xb);
  cvt_t<<<dim3(3072 / 32, DIM / 32), dim3(32, 8), 0, stream>>>(W_qkv, Wtq,
                                                               DIM, 3072);
  cvt_t<<<dim3(DIM / 32, DIM / 32), dim3(32, 8), 0, stream>>>(W_proj, Wtp,
                                                              DIM, DIM);

  qkv_mfma<<<dim3(3072 / 128, NROWS / 128), 256, 0, stream>>>(
      xb, Wtq, b_qkv, Qb, Kb, Vtb);

  flash_mfma<<<dim3(BATCH * NH * (SEQ / 64)), 256, 0, stream>>>(Qb, Kb, Vtb,
                                                                Abf);

  proj_mfma<<<dim3(DIM / 128, NROWS / 128), 256, 0, stream>>>(
      Abf, Wtp, b_proj, out);
}